// Round 1
// baseline (320.625 us; speedup 1.0000x reference)
//
#include <hip/hip_runtime.h>
#include <cstdint>
#include <cstddef>

#define B_  32
#define CIN 128
#define P_  256
#define E_  512
#define H_  64
#define W_  64
#define HO  32
#define WO  32

// ---------------- K1: bias GEMMs: b1=(silu(emb)@m1_w.T+m1_b), b2, b3 ----------------
__global__ void k_bias(const float* __restrict__ emb,
                       const float* __restrict__ m1_w, const float* __restrict__ m1_b,
                       const float* __restrict__ m2_w, const float* __restrict__ m2_b,
                       const float* __restrict__ m3_w, const float* __restrict__ m3_b,
                       float* __restrict__ b1, float* __restrict__ b2, float* __restrict__ b3) {
    __shared__ float se[E_];
    int n = blockIdx.x;
    for (int k = threadIdx.x; k < E_; k += blockDim.x) {
        float e = emb[n * E_ + k];
        se[k] = e / (1.f + expf(-e));   // silu
    }
    __syncthreads();
    for (int idx = threadIdx.x; idx < CIN + P_ + P_; idx += blockDim.x) {
        const float* wrow; float bias; float* dst;
        if (idx < CIN)            { wrow = m1_w + (size_t)idx * E_;          bias = m1_b[idx];       dst = b1 + n * CIN + idx; }
        else if (idx < CIN + P_)  { int c = idx - CIN;      wrow = m2_w + (size_t)c * E_; bias = m2_b[c]; dst = b2 + n * P_ + c; }
        else                      { int c = idx - CIN - P_; wrow = m3_w + (size_t)c * E_; bias = m3_b[c]; dst = b3 + n * P_ + c; }
        float acc = 0.f;
        #pragma unroll 8
        for (int k = 0; k < E_; k++) acc += se[k] * wrow[k];
        *dst = acc + bias;
    }
}

// ---------------- K2: per-out-channel scale sf + bit-packed weight signs ----------------
// wbits layout: [oc(256)][tap(9)][word(4)]  bit b of word wd = (w[oc][wd*32+b][tap] < 0)
__global__ void k_wprep(const float* __restrict__ conv_w,
                        float* __restrict__ sf, unsigned int* __restrict__ wbits) {
    int oc = blockIdx.x;        // br*128 + o
    int i  = threadIdx.x;       // input channel 0..127
    const float* wp = conv_w + ((size_t)oc * CIN + i) * 9;
    float w[9]; float s = 0.f;
    #pragma unroll
    for (int t = 0; t < 9; t++) { w[t] = wp[t]; s += fabsf(w[t]); }
    int wave = i >> 6, lane = i & 63;
    #pragma unroll
    for (int t = 0; t < 9; t++) {
        unsigned long long m = __ballot(w[t] < 0.f);
        if (lane == 0) {
            wbits[oc * 36 + t * 4 + wave * 2 + 0] = (unsigned int)(m & 0xffffffffull);
            wbits[oc * 36 + t * 4 + wave * 2 + 1] = (unsigned int)(m >> 32);
        }
    }
    __shared__ float red[128];
    red[i] = s; __syncthreads();
    for (int st = 64; st > 0; st >>= 1) {
        if (i < st) red[i] += red[i + st];
        __syncthreads();
    }
    if (i == 0) sf[oc] = red[0] / 1152.f;
}

// ---------------- K3: sign(x + b1) bit-pack: abits[n][h][w][4 words] ----------------
__global__ void k_abits(const float* __restrict__ x, const float* __restrict__ b1,
                        unsigned int* __restrict__ abits) {
    int idx = blockIdx.x * blockDim.x + threadIdx.x;   // 0..131071 = (n,h,w)
    int w = idx & 63, h = (idx >> 6) & 63, n = idx >> 12;
    const float* xpp = x + ((size_t)n * CIN) * (H_ * W_) + h * W_ + w;
    const float* bp = b1 + n * CIN;
    unsigned int words[4];
    #pragma unroll
    for (int wd = 0; wd < 4; wd++) {
        unsigned int m = 0;
        #pragma unroll
        for (int b = 0; b < 32; b++) {
            int c = wd * 32 + b;
            float v = xpp[(size_t)c * (H_ * W_)] + bp[c];
            m |= (v < 0.f ? 1u : 0u) << b;
        }
        words[wd] = m;
    }
    ((uint4*)abits)[idx] = make_uint4(words[0], words[1], words[2], words[3]);
}

// ---------------- K3b: 2x2 avgpool of x ----------------
__global__ void k_xp(const float* __restrict__ x, float* __restrict__ xpool) {
    int idx = blockIdx.x * blockDim.x + threadIdx.x;   // 0..4194303 = (n,c,h,w)
    int w = idx & 31, h = (idx >> 5) & 31;
    int c = (idx >> 10) & 127, n = idx >> 17;
    const float* p = x + (((size_t)n * CIN + c) * H_ + 2 * h) * W_ + 2 * w;
    float2 a = *(const float2*)p;
    float2 b = *(const float2*)(p + W_);
    xpool[idx] = 0.25f * (a.x + a.y + b.x + b.y);
}

// ---------------- K4: XNOR conv, stride 2, pad 1. y (pre-BN, no conv_b) -> d_out ----------------
__global__ void __launch_bounds__(256) k_conv(const unsigned int* __restrict__ abits,
                                              const unsigned int* __restrict__ wbits,
                                              const float* __restrict__ sf,
                                              float* __restrict__ y) {
    __shared__ __align__(16) unsigned int simg[H_ * W_ * 4];   // 64 KiB
    __shared__ __align__(16) unsigned int swb[32 * 36];        // 4.5 KiB
    int n = blockIdx.x >> 3, chunk = blockIdx.x & 7;           // chunk of 32 out channels

    const uint4* src = ((const uint4*)abits) + (size_t)n * (H_ * W_);
    uint4* dst = (uint4*)simg;
    for (int i = threadIdx.x; i < H_ * W_; i += 256) dst[i] = src[i];
    const uint4* wsrc = ((const uint4*)wbits) + (size_t)chunk * 32 * 9;
    for (int i = threadIdx.x; i < 32 * 9; i += 256) ((uint4*)swb)[i] = wsrc[i];
    __syncthreads();

    for (int o = 0; o < 32; o++) {
        int oc = chunk * 32 + o;
        unsigned int wreg[36];
        #pragma unroll
        for (int t = 0; t < 36; t++) wreg[t] = swb[o * 36 + t];
        float scale = sf[oc];
        for (int p = threadIdx.x; p < HO * WO; p += 256) {
            int ow = p & 31, oh = p >> 5;
            int sum = 0;
            #pragma unroll
            for (int kh = 0; kh < 3; kh++) {
                int r = 2 * oh - 1 + kh;
                if (r < 0 || r >= H_) continue;
                #pragma unroll
                for (int kw = 0; kw < 3; kw++) {
                    int cc = 2 * ow - 1 + kw;
                    if (cc < 0 || cc >= W_) continue;
                    uint4 a = *(const uint4*)&simg[(r * W_ + cc) * 4];
                    const unsigned int* wp = &wreg[(kh * 3 + kw) * 4];
                    int pop = __popc(a.x ^ wp[0]) + __popc(a.y ^ wp[1]) +
                              __popc(a.z ^ wp[2]) + __popc(a.w ^ wp[3]);
                    sum += 128 - 2 * pop;
                }
            }
            y[(((size_t)n * P_ + oc) << 10) + p] = scale * (float)sum;
        }
    }
}

// ---------------- K5: per-channel BN stats over (N,H,W) ----------------
__global__ void k_stats(const float* __restrict__ y,
                        float* __restrict__ meanv, float* __restrict__ rstdv) {
    int c = blockIdx.x;   // 0..255
    float s = 0.f, s2 = 0.f;
    for (int n = 0; n < B_; n++) {
        const float* p = y + (((size_t)n * P_ + c) << 10);
        for (int i = threadIdx.x; i < HO * WO; i += 256) {
            float v = p[i]; s += v; s2 += v * v;
        }
    }
    __shared__ float rs[256], rs2[256];
    rs[threadIdx.x] = s; rs2[threadIdx.x] = s2; __syncthreads();
    for (int st = 128; st > 0; st >>= 1) {
        if (threadIdx.x < st) { rs[threadIdx.x] += rs[threadIdx.x + st]; rs2[threadIdx.x] += rs2[threadIdx.x + st]; }
        __syncthreads();
    }
    if (threadIdx.x == 0) {
        const float inv = 1.f / (B_ * HO * WO);
        float m = rs[0] * inv;
        float var = rs2[0] * inv - m * m;
        meanv[c] = m;
        rstdv[c] = rsqrtf(var + 1e-5f);
    }
}

// ---------------- K6: fused BN-apply + skip(xp) + bias2 + PReLU + bias3 (in-place on d_out) ----------------
__global__ void k_epi(float* __restrict__ y, const float* __restrict__ xpool,
                      const float* __restrict__ meanv, const float* __restrict__ rstdv,
                      const float* __restrict__ bn_g, const float* __restrict__ bn_b,
                      const float* __restrict__ b2, const float* __restrict__ b3,
                      const float* __restrict__ prelu_a) {
    int i4 = blockIdx.x * blockDim.x + threadIdx.x;   // float4 index
    int pix4 = i4 & 255;
    int c = (i4 >> 8) & 255;
    int n = i4 >> 16;
    float4 yv = ((const float4*)y)[i4];
    float4 xv = ((const float4*)xpool)[((n * CIN + (c & 127)) << 8) + pix4];
    float m = meanv[c], r = rstdv[c] * bn_g[c];
    float add0 = bn_b[c] + b2[n * P_ + c];
    float a = prelu_a[c];
    float b3v = b3[n * P_ + c];
    float o0 = (yv.x - m) * r + add0 + xv.x; o0 = (o0 > 0.f ? o0 : a * o0) + b3v;
    float o1 = (yv.y - m) * r + add0 + xv.y; o1 = (o1 > 0.f ? o1 : a * o1) + b3v;
    float o2 = (yv.z - m) * r + add0 + xv.z; o2 = (o2 > 0.f ? o2 : a * o2) + b3v;
    float o3 = (yv.w - m) * r + add0 + xv.w; o3 = (o3 > 0.f ? o3 : a * o3) + b3v;
    ((float4*)y)[i4] = make_float4(o0, o1, o2, o3);
}

extern "C" void kernel_launch(void* const* d_in, const int* in_sizes, int n_in,
                              void* d_out, int out_size, void* d_ws, size_t ws_size,
                              hipStream_t stream) {
    const float* x      = (const float*)d_in[0];
    const float* emb    = (const float*)d_in[1];
    const float* m1_w   = (const float*)d_in[2];
    const float* m1_b   = (const float*)d_in[3];
    const float* conv_w = (const float*)d_in[4];
    // d_in[5] = conv_b : cancels exactly under training-mode BN, unused
    const float* bn_g   = (const float*)d_in[6];
    const float* bn_b   = (const float*)d_in[7];
    const float* m2_w   = (const float*)d_in[8];
    const float* m2_b   = (const float*)d_in[9];
    const float* prelu_a= (const float*)d_in[10];
    const float* m3_w   = (const float*)d_in[11];
    const float* m3_b   = (const float*)d_in[12];

    float* y = (float*)d_out;   // 32*256*32*32 f32 = 32 MiB; used as pre-BN buffer, finalized in-place

    // workspace carve-up (f32 words)
    float* wsf = (float*)d_ws;
    float* b1    = wsf;                 // 32*128
    float* b2    = wsf + 4096;          // 32*256
    float* b3    = wsf + 12288;         // 32*256
    float* sf    = wsf + 20480;         // 256
    float* meanv = wsf + 20736;         // 256
    float* rstdv = wsf + 20992;         // 256
    unsigned int* wbits = (unsigned int*)(wsf + 21248);   // 256*36 u32
    unsigned int* abits = (unsigned int*)(wsf + 30464);   // 32*64*64*4 u32 (2 MiB)
    float* xpool = wsf + 554752;        // 32*128*32*32 f32 (16 MiB)

    k_bias <<<B_, 256, 0, stream>>>(emb, m1_w, m1_b, m2_w, m2_b, m3_w, m3_b, b1, b2, b3);
    k_wprep<<<P_, 128, 0, stream>>>(conv_w, sf, wbits);
    k_abits<<<(B_ * H_ * W_) / 256, 256, 0, stream>>>(x, b1, abits);
    k_xp   <<<(B_ * CIN * HO * WO) / 256, 256, 0, stream>>>(x, xpool);
    k_conv <<<B_ * 8, 256, 0, stream>>>(abits, wbits, sf, y);
    k_stats<<<P_, 256, 0, stream>>>(y, meanv, rstdv);
    k_epi  <<<(B_ * P_ * HO * WO) / (4 * 256), 256, 0, stream>>>(y, xpool, meanv, rstdv,
                                                                 bn_g, bn_b, b2, b3, prelu_a);
}

// Round 2
// 199.454 us; speedup vs baseline: 1.6075x; 1.6075x over previous
//
#include <hip/hip_runtime.h>
#include <cstdint>
#include <cstddef>

#define B_  32
#define CIN 128
#define P_  256
#define E_  512
#define H_  64
#define W_  64
#define HO  32
#define WO  32

// ---------------- K0: silu(emb) precompute + zero the stats accumulators ----------------
__global__ void k_init(const float* __restrict__ emb, float* __restrict__ se,
                       float* __restrict__ s12) {
    int i = blockIdx.x * 256 + threadIdx.x;
    if (i < B_ * E_) {
        float e = emb[i];
        se[i] = e / (1.f + expf(-e));
    } else if (i < B_ * E_ + 2 * P_) {
        s12[i - B_ * E_] = 0.f;
    }
}

// ---------------- K1: bias GEMMs, wave-per-row, coalesced ----------------
__global__ void k_bias(const float* __restrict__ se,
                       const float* __restrict__ m1_w, const float* __restrict__ m1_b,
                       const float* __restrict__ m2_w, const float* __restrict__ m2_b,
                       const float* __restrict__ m3_w, const float* __restrict__ m3_b,
                       float* __restrict__ b1, float* __restrict__ b2, float* __restrict__ b3) {
    int bid = blockIdx.x;            // n*160 + rg
    int n = bid / 160, rg = bid % 160;
    int wave = threadIdx.x >> 6, lane = threadIdx.x & 63;
    int row = rg * 4 + wave;         // 0..639
    const float* sp = se + n * E_;
    const float* wrow; float bias; float* dst;
    if (row < CIN)            { wrow = m1_w + (size_t)row * E_;           bias = m1_b[row]; dst = b1 + n * CIN + row; }
    else if (row < CIN + P_)  { int c = row - CIN;       wrow = m2_w + (size_t)c * E_; bias = m2_b[c]; dst = b2 + n * P_ + c; }
    else                      { int c = row - CIN - P_;  wrow = m3_w + (size_t)c * E_; bias = m3_b[c]; dst = b3 + n * P_ + c; }
    float acc = 0.f;
    #pragma unroll
    for (int j = 0; j < 8; j++) {
        int k = j * 64 + lane;
        acc += sp[k] * wrow[k];
    }
    #pragma unroll
    for (int off = 32; off > 0; off >>= 1) acc += __shfl_down(acc, off);
    if (lane == 0) *dst = acc + bias;
}

// ---------------- K2: per-out-channel scale sf + bit-packed weight signs ----------------
// wbits layout: [oc(256)][tap(9)][word(4)]  bit b of word wd = (w[oc][wd*32+b][tap] < 0)
__global__ void k_wprep(const float* __restrict__ conv_w,
                        float* __restrict__ sf, unsigned int* __restrict__ wbits) {
    int oc = blockIdx.x;        // br*128 + o
    int i  = threadIdx.x;       // input channel 0..127
    const float* wp = conv_w + ((size_t)oc * CIN + i) * 9;
    float w[9]; float s = 0.f;
    #pragma unroll
    for (int t = 0; t < 9; t++) { w[t] = wp[t]; s += fabsf(w[t]); }
    int wave = i >> 6, lane = i & 63;
    #pragma unroll
    for (int t = 0; t < 9; t++) {
        unsigned long long m = __ballot(w[t] < 0.f);
        if (lane == 0) {
            wbits[oc * 36 + t * 4 + wave * 2 + 0] = (unsigned int)(m & 0xffffffffull);
            wbits[oc * 36 + t * 4 + wave * 2 + 1] = (unsigned int)(m >> 32);
        }
    }
    __shared__ float red[128];
    red[i] = s; __syncthreads();
    for (int st = 64; st > 0; st >>= 1) {
        if (i < st) red[i] += red[i + st];
        __syncthreads();
    }
    if (i == 0) sf[oc] = red[0] / 1152.f;
}

// ---------------- K3: sign(x + b1) bit-pack: abits[n][h][w][4 words] ----------------
__global__ void k_abits(const float* __restrict__ x, const float* __restrict__ b1,
                        unsigned int* __restrict__ abits) {
    int idx = blockIdx.x * blockDim.x + threadIdx.x;   // 0..131071 = (n,h,w)
    int w = idx & 63, h = (idx >> 6) & 63, n = idx >> 12;
    const float* xpp = x + ((size_t)n * CIN) * (H_ * W_) + h * W_ + w;
    const float* bp = b1 + n * CIN;
    unsigned int words[4];
    #pragma unroll
    for (int wd = 0; wd < 4; wd++) {
        unsigned int m = 0;
        #pragma unroll
        for (int b = 0; b < 32; b++) {
            int c = wd * 32 + b;
            float v = xpp[(size_t)c * (H_ * W_)] + bp[c];
            m |= (v < 0.f ? 1u : 0u) << b;
        }
        words[wd] = m;
    }
    ((uint4*)abits)[idx] = make_uint4(words[0], words[1], words[2], words[3]);
}

// ---------------- K3b: 2x2 avgpool of x ----------------
__global__ void k_xp(const float* __restrict__ x, float* __restrict__ xpool) {
    int idx = blockIdx.x * blockDim.x + threadIdx.x;   // 0..4194303 = (n,c,h,w)
    int w = idx & 31, h = (idx >> 5) & 31;
    int c = (idx >> 10) & 127, n = idx >> 17;
    const float* p = x + (((size_t)n * CIN + c) * H_ + 2 * h) * W_ + 2 * w;
    float2 a = *(const float2*)p;
    float2 b = *(const float2*)(p + W_);
    xpool[idx] = 0.25f * (a.x + a.y + b.x + b.y);
}

// ---------------- K4: XNOR conv v2 — taps in VGPRs, weights broadcast from LDS ----------------
// grid: bid = n*32 + ocg*4 + strip   (32 oc per ocg, 8 output rows per strip)
__global__ void __launch_bounds__(256, 4) k_conv(const unsigned int* __restrict__ abits,
                                                 const unsigned int* __restrict__ wbits,
                                                 const float* __restrict__ sf,
                                                 float* __restrict__ y) {
    __shared__ __align__(16) uint4 swb[32 * 9];     // 4.5 KiB: this group's weights
    int bid = blockIdx.x;
    int strip = bid & 3;
    int ocg   = (bid >> 2) & 7;
    int n     = bid >> 5;
    int tid = threadIdx.x;
    int oh = strip * 8 + (tid >> 5), ow = tid & 31;

    const uint4* wsrc = ((const uint4*)wbits) + (size_t)ocg * 32 * 9;
    for (int i = tid; i < 32 * 9; i += 256) swb[i] = wsrc[i];

    // load this pixel's 9 taps into registers (abits is 2 MB -> L2-resident)
    const uint4* asrc = ((const uint4*)abits) + ((size_t)n << 12);
    uint4 img[9];
    int vmask = 0;
    #pragma unroll
    for (int kh = 0; kh < 3; kh++) {
        #pragma unroll
        for (int kw = 0; kw < 3; kw++) {
            int t = kh * 3 + kw;
            int r = 2 * oh - 1 + kh, c = 2 * ow - 1 + kw;
            bool v = (unsigned)r < 64u && (unsigned)c < 64u;
            img[t] = v ? asrc[r * 64 + c] : make_uint4(0u, 0u, 0u, 0u);
            vmask |= (v ? 1 : 0) << t;
        }
    }
    int base128 = 128 * __popc(vmask);
    __syncthreads();

    float* yp = y + (((size_t)n * P_ + ocg * 32) << 10) + strip * 256 + tid;
    const float* sfp = sf + ocg * 32;
    #pragma unroll 2
    for (int o = 0; o < 32; o++) {
        int popsum = 0;
        #pragma unroll
        for (int t = 0; t < 9; t++) {
            uint4 a = img[t];
            uint4 w = swb[o * 9 + t];               // uniform address -> LDS broadcast
            int p = __popc(a.x ^ w.x) + __popc(a.y ^ w.y) +
                    __popc(a.z ^ w.z) + __popc(a.w ^ w.w);
            popsum += ((vmask >> t) & 1) ? p : 0;
        }
        float val = sfp[o] * (float)(base128 - 2 * popsum);
        yp[(size_t)o << 10] = val;
    }
}

// ---------------- K5: BN partial sums (per channel) via block partials + atomics ----------------
__global__ void k_stats(const float* __restrict__ y,
                        float* __restrict__ s1, float* __restrict__ s2) {
    int c = blockIdx.x >> 2, q = blockIdx.x & 3;   // quarter of the batch
    int tid = threadIdx.x;
    float s = 0.f, ss = 0.f;
    for (int n = q * 8; n < q * 8 + 8; n++) {
        float4 v = ((const float4*)y)[(((size_t)n * P_ + c) << 8) + tid];
        s  += v.x + v.y + v.z + v.w;
        ss += v.x * v.x + v.y * v.y + v.z * v.z + v.w * v.w;
    }
    #pragma unroll
    for (int off = 32; off > 0; off >>= 1) {
        s += __shfl_down(s, off); ss += __shfl_down(ss, off);
    }
    __shared__ float r1[4], r2[4];
    int wave = tid >> 6, lane = tid & 63;
    if (lane == 0) { r1[wave] = s; r2[wave] = ss; }
    __syncthreads();
    if (tid == 0) {
        atomicAdd(s1 + c, r1[0] + r1[1] + r1[2] + r1[3]);
        atomicAdd(s2 + c, r2[0] + r2[1] + r2[2] + r2[3]);
    }
}

// ---------------- K6: fused BN finalize+apply + skip(xp) + bias2 + PReLU + bias3 ----------------
__global__ void k_epi(float* __restrict__ y, const float* __restrict__ xpool,
                      const float* __restrict__ s1, const float* __restrict__ s2,
                      const float* __restrict__ bn_g, const float* __restrict__ bn_b,
                      const float* __restrict__ b2, const float* __restrict__ b3,
                      const float* __restrict__ prelu_a) {
    int i4 = blockIdx.x * blockDim.x + threadIdx.x;   // float4 index
    int pix4 = i4 & 255;
    int c = (i4 >> 8) & 255;
    int n = i4 >> 16;
    float4 yv = ((const float4*)y)[i4];
    float4 xv = ((const float4*)xpool)[((n * CIN + (c & 127)) << 8) + pix4];
    const float inv = 1.f / (B_ * HO * WO);
    float m = s1[c] * inv;
    float var = fmaf(-m, m, s2[c] * inv);
    float r = rsqrtf(var + 1e-5f) * bn_g[c];
    float add0 = bn_b[c] + b2[n * P_ + c];
    float a = prelu_a[c];
    float b3v = b3[n * P_ + c];
    float o0 = (yv.x - m) * r + add0 + xv.x; o0 = (o0 > 0.f ? o0 : a * o0) + b3v;
    float o1 = (yv.y - m) * r + add0 + xv.y; o1 = (o1 > 0.f ? o1 : a * o1) + b3v;
    float o2 = (yv.z - m) * r + add0 + xv.z; o2 = (o2 > 0.f ? o2 : a * o2) + b3v;
    float o3 = (yv.w - m) * r + add0 + xv.w; o3 = (o3 > 0.f ? o3 : a * o3) + b3v;
    ((float4*)y)[i4] = make_float4(o0, o1, o2, o3);
}

extern "C" void kernel_launch(void* const* d_in, const int* in_sizes, int n_in,
                              void* d_out, int out_size, void* d_ws, size_t ws_size,
                              hipStream_t stream) {
    const float* x      = (const float*)d_in[0];
    const float* emb    = (const float*)d_in[1];
    const float* m1_w   = (const float*)d_in[2];
    const float* m1_b   = (const float*)d_in[3];
    const float* conv_w = (const float*)d_in[4];
    // d_in[5] = conv_b : cancels exactly under training-mode BN, unused
    const float* bn_g   = (const float*)d_in[6];
    const float* bn_b   = (const float*)d_in[7];
    const float* m2_w   = (const float*)d_in[8];
    const float* m2_b   = (const float*)d_in[9];
    const float* prelu_a= (const float*)d_in[10];
    const float* m3_w   = (const float*)d_in[11];
    const float* m3_b   = (const float*)d_in[12];

    float* y = (float*)d_out;   // 32 MiB pre-BN buffer, finalized in-place

    // workspace carve-up (f32 words)
    float* wsf = (float*)d_ws;
    float* se    = wsf;                  // 32*512 silu(emb)
    float* b1    = wsf + 16384;          // 32*128
    float* b2    = wsf + 20480;          // 32*256
    float* b3    = wsf + 28672;          // 32*256
    float* sf    = wsf + 36864;          // 256
    float* s1    = wsf + 37120;          // 256  (zeroed by k_init)
    float* s2    = wsf + 37376;          // 256  (zeroed by k_init)
    unsigned int* wbits = (unsigned int*)(wsf + 37632);   // 256*36 u32
    unsigned int* abits = (unsigned int*)(wsf + 46848);   // 32*64*64*4 u32 (2 MiB)
    float* xpool = wsf + 571136;         // 32*128*32*32 f32 (16 MiB)

    k_init <<<(B_ * E_ + 2 * P_ + 255) / 256, 256, 0, stream>>>(emb, se, s1);
    k_bias <<<B_ * 160, 256, 0, stream>>>(se, m1_w, m1_b, m2_w, m2_b, m3_w, m3_b, b1, b2, b3);
    k_wprep<<<P_, 128, 0, stream>>>(conv_w, sf, wbits);
    k_abits<<<(B_ * H_ * W_) / 256, 256, 0, stream>>>(x, b1, abits);
    k_xp   <<<(B_ * CIN * HO * WO) / 256, 256, 0, stream>>>(x, xpool);
    k_conv <<<B_ * 32, 256, 0, stream>>>(abits, wbits, sf, y);
    k_stats<<<P_ * 4, 256, 0, stream>>>(y, s1, s2);
    k_epi  <<<(B_ * P_ * HO * WO) / (4 * 256), 256, 0, stream>>>(y, xpool, s1, s2,
                                                                 bn_g, bn_b, b2, b3, prelu_a);
}